// Round 3
// baseline (623.434 us; speedup 1.0000x reference)
//
#include <hip/hip_runtime.h>
#include <hip/hip_fp16.h>
#include <math.h>

#define N_NODES 100000
#define N_EDGES 3200000
#define IN_DIM 11
#define HID 32
#define HID2 16
#define SCHUNK 100352   // per-array stride in ws (multiple of 128, >= N_NODES+1)
#define NBLK 391        // ceil(100000/256)
#define EB4 3125        // N_EDGES / 1024 (4 edges per thread, 256 threads)

// ---------------- direct CSR build: deg -> scan -> scatter ----------------
// deg[] lives in the `cur` array region (pre-zeroed); overwritten by cursors in k_scan3.
__global__ __launch_bounds__(256) void k_deg(const int* __restrict__ ei,
                                             int* __restrict__ deg) {
    int base = blockIdx.x * 1024 + threadIdx.x * 4;
    int4 d4 = *(const int4*)(ei + N_EDGES + base);   // dst row, coalesced 16B
    atomicAdd(&deg[d4.x], 1);
    atomicAdd(&deg[d4.y], 1);
    atomicAdd(&deg[d4.z], 1);
    atomicAdd(&deg[d4.w], 1);
}

// per-256-chunk local exclusive scan + dinv; blocksum out
__global__ __launch_bounds__(256) void k_scan1(const int* __restrict__ deg,
                                               int* __restrict__ rowstart,
                                               float* __restrict__ dinv,
                                               int* __restrict__ blocksum) {
    __shared__ int tmp[256];
    int t = threadIdx.x;
    int node = blockIdx.x * 256 + t;
    int d = (node < N_NODES) ? deg[node] : 0;
    tmp[t] = d;
    __syncthreads();
    for (int off = 1; off < 256; off <<= 1) {
        int v = (t >= off) ? tmp[t - off] : 0;
        __syncthreads();
        tmp[t] += v;
        __syncthreads();
    }
    if (node < N_NODES) {
        rowstart[node] = tmp[t] - d;                 // local exclusive prefix
        dinv[node] = rsqrtf((float)d + 1.0f);        // +1 self-loop
    }
    if (t == 255) blocksum[blockIdx.x] = tmp[255];
}

// scan of 391 block sums (single block)
__global__ __launch_bounds__(512) void k_scan2(const int* __restrict__ blocksum,
                                               int* __restrict__ basearr) {
    __shared__ int tmp[512];
    int t = threadIdx.x;
    int v = (t < NBLK) ? blocksum[t] : 0;
    tmp[t] = v;
    __syncthreads();
    for (int off = 1; off < 512; off <<= 1) {
        int u = (t >= off) ? tmp[t - off] : 0;
        __syncthreads();
        tmp[t] += u;
        __syncthreads();
    }
    if (t < NBLK) basearr[t] = tmp[t] - v;           // exclusive base per chunk
}

// add base, emit final rowstart + cursor copy (overwrites deg), sentinel
__global__ __launch_bounds__(256) void k_scan3(int* __restrict__ rowstart,
                                               const int* __restrict__ basearr,
                                               int* __restrict__ cur) {
    int node = blockIdx.x * 256 + threadIdx.x;
    if (node < N_NODES) {
        int rs = rowstart[node] + basearr[blockIdx.x];
        rowstart[node] = rs;
        cur[node] = rs;
    }
    if (blockIdx.x == 0 && threadIdx.x == 0) rowstart[N_NODES] = N_EDGES;
}

// scatter edges into CSR via per-node cursor atomics
__global__ __launch_bounds__(256) void k_scatter(const int* __restrict__ ei,
                                                 int* __restrict__ cur,
                                                 int* __restrict__ csr_src) {
    int base = blockIdx.x * 1024 + threadIdx.x * 4;
    int4 s4 = *(const int4*)(ei + base);             // src row
    int4 d4 = *(const int4*)(ei + N_EDGES + base);   // dst row
    int p0 = atomicAdd(&cur[d4.x], 1);
    int p1 = atomicAdd(&cur[d4.y], 1);
    int p2 = atomicAdd(&cur[d4.z], 1);
    int p3 = atomicAdd(&cur[d4.w], 1);
    csr_src[p0] = s4.x;
    csr_src[p1] = s4.y;
    csr_src[p2] = s4.z;
    csr_src[p3] = s4.w;
}

// ---------------- dense transform 1 (write dinv-scaled fp16, interleaved [node*32+j]) -----
__global__ void k_xw1(const float* __restrict__ x, const float* __restrict__ W1,
                      const float* __restrict__ dinv, __half* __restrict__ xwh) {
    int t = blockIdx.x * blockDim.x + threadIdx.x;
    int node = t >> 5;
    int j = t & 31;
    __shared__ float sW[IN_DIM * HID];
    __shared__ float sx[8 * IN_DIM];
    for (int i = threadIdx.x; i < IN_DIM * HID; i += 256) sW[i] = W1[i];
    int base = blockIdx.x * 8;
    if (threadIdx.x < 8 * IN_DIM) sx[threadIdx.x] = x[base * IN_DIM + threadIdx.x];
    __syncthreads();
    int ln = node - base;
    float acc = 0.0f;
#pragma unroll
    for (int k = 0; k < IN_DIM; ++k)
        acc += sx[ln * IN_DIM + k] * sW[k * HID + j];
    xwh[t] = __float2half(dinv[node] * acc);
}

// ---------------- wide edge gather (octet decomposition, unchanged from r2) ----------------
__device__ __forceinline__ void accum8(float* __restrict__ acc, const uint4 v) {
    float2 f0 = __half22float2(*(const __half2*)&v.x);
    float2 f1 = __half22float2(*(const __half2*)&v.y);
    float2 f2 = __half22float2(*(const __half2*)&v.z);
    float2 f3 = __half22float2(*(const __half2*)&v.w);
    acc[0] += f0.x; acc[1] += f0.y;
    acc[2] += f1.x; acc[3] += f1.y;
    acc[4] += f2.x; acc[5] += f2.y;
    acc[6] += f3.x; acc[7] += f3.y;
}

__device__ __forceinline__ void edge_accum8(int beg, int end, int q, int oj,
                                            const int* __restrict__ csr_src,
                                            const __half* __restrict__ xwh,
                                            float* __restrict__ acc) {
#pragma unroll
    for (int k = 0; k < 8; ++k) acc[k] = 0.0f;
    int e = beg;
    for (; e + 32 <= end; e += 32) {
        int s0 = csr_src[e + q];
        int s1 = csr_src[e + 8 + q];
        int s2 = csr_src[e + 16 + q];
        int s3 = csr_src[e + 24 + q];
        uint4 v0 = *(const uint4*)(xwh + ((s0 << 5) | oj));
        uint4 v1 = *(const uint4*)(xwh + ((s1 << 5) | oj));
        uint4 v2 = *(const uint4*)(xwh + ((s2 << 5) | oj));
        uint4 v3 = *(const uint4*)(xwh + ((s3 << 5) | oj));
        accum8(acc, v0); accum8(acc, v1); accum8(acc, v2); accum8(acc, v3);
    }
    if (e + 16 <= end) {
        int s0 = csr_src[e + q];
        int s1 = csr_src[e + 8 + q];
        uint4 v0 = *(const uint4*)(xwh + ((s0 << 5) | oj));
        uint4 v1 = *(const uint4*)(xwh + ((s1 << 5) | oj));
        accum8(acc, v0); accum8(acc, v1);
        e += 16;
    }
    if (e + 8 <= end) {
        int s0 = csr_src[e + q];
        uint4 v0 = *(const uint4*)(xwh + ((s0 << 5) | oj));
        accum8(acc, v0);
        e += 8;
    }
    if (e + q < end) {  // masked tail
        int s0 = csr_src[e + q];
        uint4 v0 = *(const uint4*)(xwh + ((s0 << 5) | oj));
        accum8(acc, v0);
    }
#pragma unroll
    for (int m = 4; m <= 16; m <<= 1) {
#pragma unroll
        for (int k = 0; k < 8; ++k) acc[k] += __shfl_xor(acc[k], m);
    }
}

// ---------------- layer-1 gather fused with bias1+relu and the W2 transform ---------------
__global__ __launch_bounds__(256) void k_gather_xw2(const int* __restrict__ rowstart,
                                                    const float* __restrict__ dinv,
                                                    const int* __restrict__ csr_src,
                                                    const __half* __restrict__ xwh1,
                                                    const float* __restrict__ b1,
                                                    const float* __restrict__ W2,
                                                    __half* __restrict__ xwh2) {
    __shared__ float sW2[HID * HID];
    __shared__ float sA[8][33];
    __shared__ float sH[8][33];
    for (int i = threadIdx.x; i < HID * HID; i += 256) sW2[i] = W2[i];

    int ln = threadIdx.x >> 5;
    int node = blockIdx.x * 8 + ln;
    int l = threadIdx.x & 31;
    int q = l >> 2;
    int oj = (l & 3) << 3;

    float acc[8];
    edge_accum8(rowstart[node], rowstart[node + 1], q, oj, csr_src, xwh1, acc);
    if (q == 0) {
#pragma unroll
        for (int k = 0; k < 8; ++k) sA[ln][oj + k] = acc[k];
    }
    __syncthreads();

    int j = l;
    float dd = dinv[node];
    float hv = dd * (sA[ln][j] + __half2float(xwh1[node * HID + j])) + b1[j];
    sH[ln][j] = hv > 0.0f ? hv : 0.0f;
    __syncthreads();

    float a2 = 0.0f;
#pragma unroll
    for (int k = 0; k < HID; ++k) a2 += sH[ln][k] * sW2[k * HID + j];
    xwh2[node * HID + j] = __float2half(dd * a2);
}

// ---------------- layer-2 gather fused with bias2+relu and the output MLP ----------------
__global__ __launch_bounds__(256) void k_gather_mlp(const int* __restrict__ rowstart,
                                                    const float* __restrict__ dinv,
                                                    const int* __restrict__ csr_src,
                                                    const __half* __restrict__ xwh,
                                                    const float* __restrict__ b2,
                                                    const float* __restrict__ Wo1,
                                                    const float* __restrict__ bo1,
                                                    const float* __restrict__ Wo2,
                                                    const float* __restrict__ bo2,
                                                    float* __restrict__ out) {
    __shared__ float sW1[HID * HID2];
    __shared__ float sb1[HID2];
    __shared__ float sW2v[HID2];
    __shared__ float sb2[HID];
    __shared__ float sA[8][33];
    __shared__ float sH[8][33];
    for (int i = threadIdx.x; i < HID * HID2; i += 256) sW1[i] = Wo1[i];
    if (threadIdx.x < HID2) {
        sb1[threadIdx.x] = bo1[threadIdx.x];
        sW2v[threadIdx.x] = Wo2[threadIdx.x];
    }
    if (threadIdx.x < HID) sb2[threadIdx.x] = b2[threadIdx.x];

    int ln = threadIdx.x >> 5;
    int node = blockIdx.x * 8 + ln;
    int l = threadIdx.x & 31;
    int q = l >> 2;
    int oj = (l & 3) << 3;

    float acc[8];
    edge_accum8(rowstart[node], rowstart[node + 1], q, oj, csr_src, xwh, acc);
    if (q == 0) {
#pragma unroll
        for (int k = 0; k < 8; ++k) sA[ln][oj + k] = acc[k];
    }
    __syncthreads();

    int j = l;
    float dd = dinv[node];
    float hv = dd * (sA[ln][j] + __half2float(xwh[node * HID + j])) + sb2[j];
    sH[ln][j] = hv > 0.0f ? hv : 0.0f;
    __syncthreads();

    float val = 0.0f;
    if (j < HID2) {
        float a = sb1[j];
#pragma unroll
        for (int k = 0; k < HID; ++k) a += sH[ln][k] * sW1[k * HID2 + j];
        a = a > 0.0f ? a : (expf(a) - 1.0f);  // elu alpha=1
        val = a * sW2v[j];
    }
#pragma unroll
    for (int d = 16; d >= 1; d >>= 1) val += __shfl_down(val, d, 32);
    if (j == 0) out[node] = val + bo2[0];
}

extern "C" void kernel_launch(void* const* d_in, const int* in_sizes, int n_in,
                              void* d_out, int out_size, void* d_ws, size_t ws_size,
                              hipStream_t stream) {
    const float* x   = (const float*)d_in[0];
    const int*   ei  = (const int*)d_in[1];
    const float* W1  = (const float*)d_in[3];
    const float* b1  = (const float*)d_in[4];
    const float* W2  = (const float*)d_in[5];
    const float* b2  = (const float*)d_in[6];
    const float* Wo1 = (const float*)d_in[7];
    const float* bo1 = (const float*)d_in[8];
    const float* Wo2 = (const float*)d_in[9];
    const float* bo2 = (const float*)d_in[10];
    float* out = (float*)d_out;

    // ws layout (4B units):
    // blocksum[512] | basearr[512] | rowstart[SCHUNK] | dinv[SCHUNK] | cur/deg[SCHUNK]
    // | csr_src[E] | XWH1[N*HID fp16] | XWH2[N*HID fp16]
    int*      blocksum = (int*)d_ws;
    int*      basearr  = blocksum + 512;
    int*      rowstart = basearr + 512;
    float*    dinv     = (float*)(rowstart + SCHUNK);
    int*      cur      = (int*)(dinv + SCHUNK);        // doubles as deg
    int*      csr_src  = cur + SCHUNK;
    __half*   XWH1     = (__half*)(csr_src + N_EDGES);
    __half*   XWH2     = XWH1 + (size_t)N_NODES * HID;

    const int BT = 256;
    int gNH  = (N_NODES * HID + BT - 1) / BT;       // 12500
    int gG   = N_NODES / 8;                         // 12500 (exact)

    // direct CSR build: deg (atomics) -> 3-level scan -> scatter (atomics)
    hipMemsetAsync(cur, 0, SCHUNK * sizeof(int), stream);
    k_deg    <<<EB4, BT, 0, stream>>>(ei, cur);
    k_scan1  <<<NBLK, BT, 0, stream>>>(cur, rowstart, dinv, blocksum);
    k_scan2  <<<1, 512, 0, stream>>>(blocksum, basearr);
    k_scan3  <<<NBLK, BT, 0, stream>>>(rowstart, basearr, cur);
    k_scatter<<<EB4, BT, 0, stream>>>(ei, cur, csr_src);

    // layer 1 (+ fused W2): XWH1 = fp16(dinv.*(x@W1)); XWH2 = fp16(dinv.*(relu(gather+b1)@W2))
    k_xw1<<<gNH, BT, 0, stream>>>(x, W1, dinv, XWH1);
    k_gather_xw2<<<gG, BT, 0, stream>>>(rowstart, dinv, csr_src, XWH1, b1, W2, XWH2);

    // layer 2 + head: out = MLP(relu(dinv.*gather(XWH2) + b2))
    k_gather_mlp<<<gG, BT, 0, stream>>>(rowstart, dinv, csr_src, XWH2,
                                        b2, Wo1, bo1, Wo2, bo2, out);
}

// Round 4
// 267.044 us; speedup vs baseline: 2.3346x; 2.3346x over previous
//
#include <hip/hip_runtime.h>
#include <hip/hip_fp16.h>
#include <math.h>

#define N_NODES 100000
#define N_EDGES 3200000
#define IN_DIM 11
#define HID 32
#define HID2 16
#define SCHUNK 100352   // per-array stride in ws (multiple of 128, >= N_NODES+1)
#define BINSHIFT 8
#define BINSZ 256
#define NB 391          // ceil(100000/256) bins (256 nodes each)
#define CHUNK 4096      // edges per chunk-block
#define NBC 782         // ceil(3200000/4096) chunk-blocks

// ---------------- binned CSR build ----------------
// Pass 1: per-chunk per-bin counts -> cnthist[bin][chunk]  (no global atomics)
__global__ __launch_bounds__(256) void k_hist(const int* __restrict__ ei,
                                              int* __restrict__ cnthist) {
    __shared__ int h[NB];
    int t = threadIdx.x;
    for (int i = t; i < NB; i += 256) h[i] = 0;
    __syncthreads();
    int b0 = blockIdx.x * CHUNK;
    int e1 = b0 + CHUNK; if (e1 > N_EDGES) e1 = N_EDGES;
    for (int e = b0 + t; e < e1; e += 256)
        atomicAdd(&h[ei[N_EDGES + e] >> BINSHIFT], 1);
    __syncthreads();
    for (int i = t; i < NB; i += 256)
        cnthist[i * NBC + blockIdx.x] = h[i];
}

// Pass 2: per-bin exclusive scan over chunks (in-place), bin totals out.
// Deterministic per-chunk bases => no global cursor atomics in scatter.
__global__ __launch_bounds__(256) void k_colscan(int* __restrict__ cnthist,
                                                 int* __restrict__ colsum) {
    __shared__ int tmp[256];
    int i = blockIdx.x;   // bin
    int t = threadIdx.x;
    int v[4];
    int s4 = 0;
#pragma unroll
    for (int u = 0; u < 4; ++u) {
        int idx = t * 4 + u;
        v[u] = (idx < NBC) ? cnthist[i * NBC + idx] : 0;
        s4 += v[u];
    }
    tmp[t] = s4;
    __syncthreads();
    for (int off = 1; off < 256; off <<= 1) {
        int u = (t >= off) ? tmp[t - off] : 0;
        __syncthreads();
        tmp[t] += u;
        __syncthreads();
    }
    int base = tmp[t] - s4;   // exclusive across 4-groups
#pragma unroll
    for (int u = 0; u < 4; ++u) {
        int idx = t * 4 + u;
        if (idx < NBC) cnthist[i * NBC + idx] = base;
        base += v[u];
    }
    if (t == 255) colsum[i] = tmp[255];
}

// Pass 3: scan of 391 bin totals -> binbase (single block)
__global__ __launch_bounds__(512) void k_scanbins(const int* __restrict__ colsum,
                                                  int* __restrict__ binbase) {
    __shared__ int tmp[512];
    int t = threadIdx.x;
    int v = (t < NB) ? colsum[t] : 0;
    tmp[t] = v;
    __syncthreads();
    for (int off = 1; off < 512; off <<= 1) {
        int u = (t >= off) ? tmp[t - off] : 0;
        __syncthreads();
        tmp[t] += u;
        __syncthreads();
    }
    if (t < NB) binbase[t] = tmp[t] - v;
    if (t == 0) binbase[NB] = N_EDGES;   // sentinel
}

// Pass 4: scatter edges into bin buckets; per-block contiguous runs per bin
// (clustered writes -- the property k_scatter lacked).
__global__ __launch_bounds__(256) void k_binscatter(const int* __restrict__ ei,
                                                    const int* __restrict__ binbase,
                                                    const int* __restrict__ cnthist,
                                                    unsigned* __restrict__ binbuf) {
    __shared__ int h[NB];
    __shared__ int base[NB];
    int t = threadIdx.x;
    for (int i = t; i < NB; i += 256) {
        base[i] = binbase[i] + cnthist[i * NBC + blockIdx.x];
        h[i] = 0;
    }
    __syncthreads();
    int b0 = blockIdx.x * CHUNK;
    int e1 = b0 + CHUNK; if (e1 > N_EDGES) e1 = N_EDGES;
    for (int e = b0 + t; e < e1; e += 256) {
        int d = ei[N_EDGES + e];
        int s = ei[e];
        int b = d >> BINSHIFT;
        int p = base[b] + atomicAdd(&h[b], 1);
        binbuf[p] = (unsigned)s | ((unsigned)(d & (BINSZ - 1)) << 17);  // s < 2^17
    }
}

// Pass 5: within each bin (block=bin), per-node counting sort -> csr_src,
// rowstart, dinv.  All writes land in the block's own 32KB window.
__global__ __launch_bounds__(512) void k_binfill(const unsigned* __restrict__ binbuf,
                                                 const int* __restrict__ binbase,
                                                 int* __restrict__ rowstart,
                                                 float* __restrict__ dinv,
                                                 int* __restrict__ csr_src) {
    int b = blockIdx.x, t = threadIdx.x;
    __shared__ int cnt[BINSZ], rloc[BINSZ], cur[BINSZ], tmp[BINSZ];
    int ebeg = binbase[b], eend = binbase[b + 1];
    if (t < BINSZ) cnt[t] = 0;
    __syncthreads();
    for (int e = ebeg + t; e < eend; e += 512)
        atomicAdd(&cnt[binbuf[e] >> 17], 1);
    __syncthreads();
    int c = 0;
    if (t < BINSZ) { c = cnt[t]; tmp[t] = c; }
    __syncthreads();
    for (int off = 1; off < BINSZ; off <<= 1) {
        int u = (t < BINSZ && t >= off) ? tmp[t - off] : 0;
        __syncthreads();
        if (t < BINSZ) tmp[t] += u;
        __syncthreads();
    }
    if (t < BINSZ) {
        rloc[t] = tmp[t] - c;
        cur[t] = 0;
        int node = b * BINSZ + t;
        if (node < N_NODES) {
            rowstart[node] = ebeg + rloc[t];
            dinv[node] = rsqrtf((float)c + 1.0f);  // +1 self-loop
        }
    }
    if (b == 0 && t == 0) rowstart[N_NODES] = N_EDGES;  // sentinel
    __syncthreads();
    for (int e = ebeg + t; e < eend; e += 512) {
        unsigned vv = binbuf[e];
        int dl = vv >> 17;
        int s = (int)(vv & 0x1FFFFu);
        int p = ebeg + rloc[dl] + atomicAdd(&cur[dl], 1);
        csr_src[p] = s;
    }
}

// ---------------- dense transform 1 (write dinv-scaled fp16, interleaved [node*32+j]) -----
__global__ void k_xw1(const float* __restrict__ x, const float* __restrict__ W1,
                      const float* __restrict__ dinv, __half* __restrict__ xwh) {
    int t = blockIdx.x * blockDim.x + threadIdx.x;
    int node = t >> 5;
    int j = t & 31;
    __shared__ float sW[IN_DIM * HID];
    __shared__ float sx[8 * IN_DIM];
    for (int i = threadIdx.x; i < IN_DIM * HID; i += 256) sW[i] = W1[i];
    int base = blockIdx.x * 8;
    if (threadIdx.x < 8 * IN_DIM) sx[threadIdx.x] = x[base * IN_DIM + threadIdx.x];
    __syncthreads();
    int ln = node - base;
    float acc = 0.0f;
#pragma unroll
    for (int k = 0; k < IN_DIM; ++k)
        acc += sx[ln * IN_DIM + k] * sW[k * HID + j];
    xwh[t] = __float2half(dinv[node] * acc);
}

// ---------------- wide edge gather (octet decomposition, unchanged from r2) ----------------
__device__ __forceinline__ void accum8(float* __restrict__ acc, const uint4 v) {
    float2 f0 = __half22float2(*(const __half2*)&v.x);
    float2 f1 = __half22float2(*(const __half2*)&v.y);
    float2 f2 = __half22float2(*(const __half2*)&v.z);
    float2 f3 = __half22float2(*(const __half2*)&v.w);
    acc[0] += f0.x; acc[1] += f0.y;
    acc[2] += f1.x; acc[3] += f1.y;
    acc[4] += f2.x; acc[5] += f2.y;
    acc[6] += f3.x; acc[7] += f3.y;
}

__device__ __forceinline__ void edge_accum8(int beg, int end, int q, int oj,
                                            const int* __restrict__ csr_src,
                                            const __half* __restrict__ xwh,
                                            float* __restrict__ acc) {
#pragma unroll
    for (int k = 0; k < 8; ++k) acc[k] = 0.0f;
    int e = beg;
    for (; e + 32 <= end; e += 32) {
        int s0 = csr_src[e + q];
        int s1 = csr_src[e + 8 + q];
        int s2 = csr_src[e + 16 + q];
        int s3 = csr_src[e + 24 + q];
        uint4 v0 = *(const uint4*)(xwh + ((s0 << 5) | oj));
        uint4 v1 = *(const uint4*)(xwh + ((s1 << 5) | oj));
        uint4 v2 = *(const uint4*)(xwh + ((s2 << 5) | oj));
        uint4 v3 = *(const uint4*)(xwh + ((s3 << 5) | oj));
        accum8(acc, v0); accum8(acc, v1); accum8(acc, v2); accum8(acc, v3);
    }
    if (e + 16 <= end) {
        int s0 = csr_src[e + q];
        int s1 = csr_src[e + 8 + q];
        uint4 v0 = *(const uint4*)(xwh + ((s0 << 5) | oj));
        uint4 v1 = *(const uint4*)(xwh + ((s1 << 5) | oj));
        accum8(acc, v0); accum8(acc, v1);
        e += 16;
    }
    if (e + 8 <= end) {
        int s0 = csr_src[e + q];
        uint4 v0 = *(const uint4*)(xwh + ((s0 << 5) | oj));
        accum8(acc, v0);
        e += 8;
    }
    if (e + q < end) {  // masked tail
        int s0 = csr_src[e + q];
        uint4 v0 = *(const uint4*)(xwh + ((s0 << 5) | oj));
        accum8(acc, v0);
    }
#pragma unroll
    for (int m = 4; m <= 16; m <<= 1) {
#pragma unroll
        for (int k = 0; k < 8; ++k) acc[k] += __shfl_xor(acc[k], m);
    }
}

// ---------------- layer-1 gather fused with bias1+relu and the W2 transform ---------------
__global__ __launch_bounds__(256) void k_gather_xw2(const int* __restrict__ rowstart,
                                                    const float* __restrict__ dinv,
                                                    const int* __restrict__ csr_src,
                                                    const __half* __restrict__ xwh1,
                                                    const float* __restrict__ b1,
                                                    const float* __restrict__ W2,
                                                    __half* __restrict__ xwh2) {
    __shared__ float sW2[HID * HID];
    __shared__ float sA[8][33];
    __shared__ float sH[8][33];
    for (int i = threadIdx.x; i < HID * HID; i += 256) sW2[i] = W2[i];

    int ln = threadIdx.x >> 5;
    int node = blockIdx.x * 8 + ln;
    int l = threadIdx.x & 31;
    int q = l >> 2;
    int oj = (l & 3) << 3;

    float acc[8];
    edge_accum8(rowstart[node], rowstart[node + 1], q, oj, csr_src, xwh1, acc);
    if (q == 0) {
#pragma unroll
        for (int k = 0; k < 8; ++k) sA[ln][oj + k] = acc[k];
    }
    __syncthreads();

    int j = l;
    float dd = dinv[node];
    float hv = dd * (sA[ln][j] + __half2float(xwh1[node * HID + j])) + b1[j];
    sH[ln][j] = hv > 0.0f ? hv : 0.0f;
    __syncthreads();

    float a2 = 0.0f;
#pragma unroll
    for (int k = 0; k < HID; ++k) a2 += sH[ln][k] * sW2[k * HID + j];
    xwh2[node * HID + j] = __float2half(dd * a2);
}

// ---------------- layer-2 gather fused with bias2+relu and the output MLP ----------------
__global__ __launch_bounds__(256) void k_gather_mlp(const int* __restrict__ rowstart,
                                                    const float* __restrict__ dinv,
                                                    const int* __restrict__ csr_src,
                                                    const __half* __restrict__ xwh,
                                                    const float* __restrict__ b2,
                                                    const float* __restrict__ Wo1,
                                                    const float* __restrict__ bo1,
                                                    const float* __restrict__ Wo2,
                                                    const float* __restrict__ bo2,
                                                    float* __restrict__ out) {
    __shared__ float sW1[HID * HID2];
    __shared__ float sb1[HID2];
    __shared__ float sW2v[HID2];
    __shared__ float sb2[HID];
    __shared__ float sA[8][33];
    __shared__ float sH[8][33];
    for (int i = threadIdx.x; i < HID * HID2; i += 256) sW1[i] = Wo1[i];
    if (threadIdx.x < HID2) {
        sb1[threadIdx.x] = bo1[threadIdx.x];
        sW2v[threadIdx.x] = Wo2[threadIdx.x];
    }
    if (threadIdx.x < HID) sb2[threadIdx.x] = b2[threadIdx.x];

    int ln = threadIdx.x >> 5;
    int node = blockIdx.x * 8 + ln;
    int l = threadIdx.x & 31;
    int q = l >> 2;
    int oj = (l & 3) << 3;

    float acc[8];
    edge_accum8(rowstart[node], rowstart[node + 1], q, oj, csr_src, xwh, acc);
    if (q == 0) {
#pragma unroll
        for (int k = 0; k < 8; ++k) sA[ln][oj + k] = acc[k];
    }
    __syncthreads();

    int j = l;
    float dd = dinv[node];
    float hv = dd * (sA[ln][j] + __half2float(xwh[node * HID + j])) + sb2[j];
    sH[ln][j] = hv > 0.0f ? hv : 0.0f;
    __syncthreads();

    float val = 0.0f;
    if (j < HID2) {
        float a = sb1[j];
#pragma unroll
        for (int k = 0; k < HID; ++k) a += sH[ln][k] * sW1[k * HID2 + j];
        a = a > 0.0f ? a : (expf(a) - 1.0f);  // elu alpha=1
        val = a * sW2v[j];
    }
#pragma unroll
    for (int d = 16; d >= 1; d >>= 1) val += __shfl_down(val, d, 32);
    if (j == 0) out[node] = val + bo2[0];
}

extern "C" void kernel_launch(void* const* d_in, const int* in_sizes, int n_in,
                              void* d_out, int out_size, void* d_ws, size_t ws_size,
                              hipStream_t stream) {
    const float* x   = (const float*)d_in[0];
    const int*   ei  = (const int*)d_in[1];
    const float* W1  = (const float*)d_in[3];
    const float* b1  = (const float*)d_in[4];
    const float* W2  = (const float*)d_in[5];
    const float* b2  = (const float*)d_in[6];
    const float* Wo1 = (const float*)d_in[7];
    const float* bo1 = (const float*)d_in[8];
    const float* Wo2 = (const float*)d_in[9];
    const float* bo2 = (const float*)d_in[10];
    float* out = (float*)d_out;

    // ws layout (4B units) -- byte-identical footprint to round-0:
    // colsum[512] | binbase[512] | rowstart[SCHUNK] | dinv[SCHUNK]
    // | csr_src[E] (cnthist[NB*NBC]=1.2MB aliases here; dead before binfill writes)
    // | binbuf[E] | XWH1[N*HID fp16] | XWH2[N*HID fp16]
    int*      colsum   = (int*)d_ws;
    int*      binbase  = colsum + 512;
    int*      rowstart = binbase + 512;
    float*    dinv     = (float*)(rowstart + SCHUNK);
    int*      csr_src  = (int*)(dinv + SCHUNK);
    unsigned* binbuf   = (unsigned*)(csr_src + N_EDGES);
    __half*   XWH1     = (__half*)(binbuf + N_EDGES);
    __half*   XWH2     = XWH1 + (size_t)N_NODES * HID;
    int*      cnthist  = csr_src;   // alias: NB*NBC = 305762 ints << N_EDGES

    const int BT = 256;
    int gNH  = (N_NODES * HID + BT - 1) / BT;       // 12500
    int gG   = N_NODES / 8;                         // 12500 (exact)

    // binned CSR build: hist -> colscan -> binscan -> scatter -> fill
    k_hist      <<<NBC, BT, 0, stream>>>(ei, cnthist);
    k_colscan   <<<NB, BT, 0, stream>>>(cnthist, colsum);
    k_scanbins  <<<1, 512, 0, stream>>>(colsum, binbase);
    k_binscatter<<<NBC, BT, 0, stream>>>(ei, binbase, cnthist, binbuf);
    k_binfill   <<<NB, 512, 0, stream>>>(binbuf, binbase, rowstart, dinv, csr_src);

    // layer 1 (+ fused W2): XWH1 = fp16(dinv.*(x@W1)); XWH2 = fp16(dinv.*(relu(gather+b1)@W2))
    k_xw1<<<gNH, BT, 0, stream>>>(x, W1, dinv, XWH1);
    k_gather_xw2<<<gG, BT, 0, stream>>>(rowstart, dinv, csr_src, XWH1, b1, W2, XWH2);

    // layer 2 + head: out = MLP(relu(dinv.*gather(XWH2) + b2))
    k_gather_mlp<<<gG, BT, 0, stream>>>(rowstart, dinv, csr_src, XWH2,
                                        b2, Wo1, bo1, Wo2, bo2, out);
}

// Round 5
// 252.576 us; speedup vs baseline: 2.4683x; 1.0573x over previous
//
#include <hip/hip_runtime.h>
#include <hip/hip_fp16.h>
#include <math.h>

#define N_NODES 100000
#define N_EDGES 3200000
#define IN_DIM 11
#define HID 32
#define HID2 16
#define SCHUNK 100352   // per-array stride in ws (multiple of 128, >= N_NODES+1)
#define BINSHIFT 8
#define BINSZ 256
#define NB 391          // ceil(100000/256) bins (256 nodes each)
#define CHUNK 4096      // edges per chunk
#define NCH 782         // ceil(3200000/4096) chunks

// ---------------- binned CSR build ----------------
// Pass 1: per-chunk per-bin counts -> cnthist[bin][chunk]  (no global atomics)
__global__ __launch_bounds__(256) void k_hist(const int* __restrict__ ei,
                                              int* __restrict__ cnthist) {
    __shared__ int h[NB];
    int t = threadIdx.x;
    for (int i = t; i < NB; i += 256) h[i] = 0;
    __syncthreads();
    int b0 = blockIdx.x * CHUNK;
    int n = N_EDGES - b0; if (n > CHUNK) n = CHUNK;   // always multiple of 4
    for (int e = t * 4; e < n; e += 1024) {
        int4 d4 = *(const int4*)(ei + N_EDGES + b0 + e);
        atomicAdd(&h[d4.x >> BINSHIFT], 1);
        atomicAdd(&h[d4.y >> BINSHIFT], 1);
        atomicAdd(&h[d4.z >> BINSHIFT], 1);
        atomicAdd(&h[d4.w >> BINSHIFT], 1);
    }
    __syncthreads();
    for (int i = t; i < NB; i += 256)
        cnthist[i * NCH + blockIdx.x] = h[i];
}

// Pass 2: per-bin exclusive scan over chunks (in-place), bin totals out.
__global__ __launch_bounds__(256) void k_colscan(int* __restrict__ cnthist,
                                                 int* __restrict__ colsum) {
    __shared__ int tmp[256];
    int i = blockIdx.x;   // bin
    int t = threadIdx.x;
    int v[4];
    int s4 = 0;
#pragma unroll
    for (int u = 0; u < 4; ++u) {
        int idx = t * 4 + u;
        v[u] = (idx < NCH) ? cnthist[i * NCH + idx] : 0;
        s4 += v[u];
    }
    tmp[t] = s4;
    __syncthreads();
    for (int off = 1; off < 256; off <<= 1) {
        int u = (t >= off) ? tmp[t - off] : 0;
        __syncthreads();
        tmp[t] += u;
        __syncthreads();
    }
    int base = tmp[t] - s4;   // exclusive across 4-groups
#pragma unroll
    for (int u = 0; u < 4; ++u) {
        int idx = t * 4 + u;
        if (idx < NCH) cnthist[i * NCH + idx] = base;
        base += v[u];
    }
    if (t == 255) colsum[i] = tmp[255];
}

// Pass 3: scan of 391 bin totals -> binbase (single block)
__global__ __launch_bounds__(512) void k_scanbins(const int* __restrict__ colsum,
                                                  int* __restrict__ binbase) {
    __shared__ int tmp[512];
    int t = threadIdx.x;
    int v = (t < NB) ? colsum[t] : 0;
    tmp[t] = v;
    __syncthreads();
    for (int off = 1; off < 512; off <<= 1) {
        int u = (t >= off) ? tmp[t - off] : 0;
        __syncthreads();
        tmp[t] += u;
        __syncthreads();
    }
    if (t < NB) binbase[t] = tmp[t] - v;
    if (t == 0) binbase[NB] = N_EDGES;   // sentinel
}

// Pass 4: scatter edges into bin buckets.  The chunk is bin-sorted in LDS
// first, then dumped linearly: consecutive threads write consecutive sorted
// positions -> per-wave stores hit a handful of lines (vs 64 scattered), and
// each global line is written in one burst (kills the L2 partial-line
// eviction RMW seen as 74.8MB WRITE_SIZE in r4).
__global__ __launch_bounds__(512) void k_binscatter(const int* __restrict__ ei,
                                                    const int* __restrict__ binbase,
                                                    const int* __restrict__ cnthist,
                                                    unsigned* __restrict__ binbuf) {
    __shared__ unsigned short sbin[CHUNK];   // bin per edge (load order)
    __shared__ unsigned char  sdl[CHUNK];    // dst-local per edge
    __shared__ unsigned       srecS[CHUNK];  // records at sorted position
    __shared__ unsigned short sbinS[CHUNK];  // bin at sorted position
    __shared__ int h[NB], rl[NB], gb[NB];
    __shared__ int tmp[512];
    int t = threadIdx.x;
    int b0 = blockIdx.x * CHUNK;
    int n = N_EDGES - b0; if (n > CHUNK) n = CHUNK;
    for (int i = t; i < NB; i += 512) h[i] = 0;
    __syncthreads();
    for (int e = t; e < n; e += 512) {
        int d = ei[N_EDGES + b0 + e];
        int b = d >> BINSHIFT;
        sbin[e] = (unsigned short)b;
        sdl[e]  = (unsigned char)(d & (BINSZ - 1));
        atomicAdd(&h[b], 1);
    }
    __syncthreads();
    int c = (t < NB) ? h[t] : 0;
    tmp[t] = c;
    __syncthreads();
    for (int off = 1; off < 512; off <<= 1) {
        int u = (t >= off) ? tmp[t - off] : 0;
        __syncthreads();
        tmp[t] += u;
        __syncthreads();
    }
    if (t < NB) {
        rl[t] = tmp[t] - c;                               // local sorted base
        gb[t] = binbase[t] + cnthist[t * NCH + blockIdx.x]; // global dump base
        h[t] = 0;                                          // reuse as cursor
    }
    __syncthreads();
    for (int e = t; e < n; e += 512) {
        int s = ei[b0 + e];            // coalesced re-read of src row
        int b = sbin[e];
        int p = rl[b] + atomicAdd(&h[b], 1);
        srecS[p] = (unsigned)s | ((unsigned)sdl[e] << 17);  // s < 2^17
        sbinS[p] = (unsigned short)b;
    }
    __syncthreads();
    for (int p = t; p < n; p += 512) {
        int b = sbinS[p];
        binbuf[gb[b] + (p - rl[b])] = srecS[p];
    }
}

// Pass 5: within each bin, per-node counting sort -> csr_src, rowstart, dinv.
// Half-bin split: 2 blocks per bin (782 blocks, no 391-block tail).  Both
// halves hist the full bin; each scatters only its own 128 nodes' edges.
__global__ __launch_bounds__(256) void k_binfill(const unsigned* __restrict__ binbuf,
                                                 const int* __restrict__ binbase,
                                                 int* __restrict__ rowstart,
                                                 float* __restrict__ dinv,
                                                 int* __restrict__ csr_src) {
    int bb = blockIdx.x;
    int b = bb >> 1;        // bin
    int half = bb & 1;      // node range [half*128, half*128+128)
    int t = threadIdx.x;
    __shared__ int cnt[BINSZ], rloc[BINSZ], cur[BINSZ], tmp[BINSZ];
    int ebeg = binbase[b], eend = binbase[b + 1];
    cnt[t] = 0;
    __syncthreads();
    for (int e = ebeg + t; e < eend; e += 256)
        atomicAdd(&cnt[binbuf[e] >> 17], 1);
    __syncthreads();
    int c = cnt[t];
    tmp[t] = c;
    __syncthreads();
    for (int off = 1; off < 256; off <<= 1) {
        int u = (t >= off) ? tmp[t - off] : 0;
        __syncthreads();
        tmp[t] += u;
        __syncthreads();
    }
    rloc[t] = tmp[t] - c;
    cur[t] = 0;
    int node = b * BINSZ + t;
    if ((t >> 7) == half && node < N_NODES) {
        rowstart[node] = ebeg + rloc[t];
        dinv[node] = rsqrtf((float)c + 1.0f);  // +1 self-loop
    }
    if (bb == 0 && t == 0) rowstart[N_NODES] = N_EDGES;  // sentinel
    __syncthreads();
    for (int e = ebeg + t; e < eend; e += 256) {
        unsigned vv = binbuf[e];
        int dl = vv >> 17;
        if ((dl >> 7) == half) {
            int p = ebeg + rloc[dl] + atomicAdd(&cur[dl], 1);
            csr_src[p] = (int)(vv & 0x1FFFFu);
        }
    }
}

// ---------------- dense transform 1 (write dinv-scaled fp16, interleaved [node*32+j]) -----
__global__ void k_xw1(const float* __restrict__ x, const float* __restrict__ W1,
                      const float* __restrict__ dinv, __half* __restrict__ xwh) {
    int t = blockIdx.x * blockDim.x + threadIdx.x;
    int node = t >> 5;
    int j = t & 31;
    __shared__ float sW[IN_DIM * HID];
    __shared__ float sx[8 * IN_DIM];
    for (int i = threadIdx.x; i < IN_DIM * HID; i += 256) sW[i] = W1[i];
    int base = blockIdx.x * 8;
    if (threadIdx.x < 8 * IN_DIM) sx[threadIdx.x] = x[base * IN_DIM + threadIdx.x];
    __syncthreads();
    int ln = node - base;
    float acc = 0.0f;
#pragma unroll
    for (int k = 0; k < IN_DIM; ++k)
        acc += sx[ln * IN_DIM + k] * sW[k * HID + j];
    xwh[t] = __float2half(dinv[node] * acc);
}

// ---------------- wide edge gather (octet decomposition, unchanged) ----------------
__device__ __forceinline__ void accum8(float* __restrict__ acc, const uint4 v) {
    float2 f0 = __half22float2(*(const __half2*)&v.x);
    float2 f1 = __half22float2(*(const __half2*)&v.y);
    float2 f2 = __half22float2(*(const __half2*)&v.z);
    float2 f3 = __half22float2(*(const __half2*)&v.w);
    acc[0] += f0.x; acc[1] += f0.y;
    acc[2] += f1.x; acc[3] += f1.y;
    acc[4] += f2.x; acc[5] += f2.y;
    acc[6] += f3.x; acc[7] += f3.y;
}

__device__ __forceinline__ void edge_accum8(int beg, int end, int q, int oj,
                                            const int* __restrict__ csr_src,
                                            const __half* __restrict__ xwh,
                                            float* __restrict__ acc) {
#pragma unroll
    for (int k = 0; k < 8; ++k) acc[k] = 0.0f;
    int e = beg;
    for (; e + 32 <= end; e += 32) {
        int s0 = csr_src[e + q];
        int s1 = csr_src[e + 8 + q];
        int s2 = csr_src[e + 16 + q];
        int s3 = csr_src[e + 24 + q];
        uint4 v0 = *(const uint4*)(xwh + ((s0 << 5) | oj));
        uint4 v1 = *(const uint4*)(xwh + ((s1 << 5) | oj));
        uint4 v2 = *(const uint4*)(xwh + ((s2 << 5) | oj));
        uint4 v3 = *(const uint4*)(xwh + ((s3 << 5) | oj));
        accum8(acc, v0); accum8(acc, v1); accum8(acc, v2); accum8(acc, v3);
    }
    if (e + 16 <= end) {
        int s0 = csr_src[e + q];
        int s1 = csr_src[e + 8 + q];
        uint4 v0 = *(const uint4*)(xwh + ((s0 << 5) | oj));
        uint4 v1 = *(const uint4*)(xwh + ((s1 << 5) | oj));
        accum8(acc, v0); accum8(acc, v1);
        e += 16;
    }
    if (e + 8 <= end) {
        int s0 = csr_src[e + q];
        uint4 v0 = *(const uint4*)(xwh + ((s0 << 5) | oj));
        accum8(acc, v0);
        e += 8;
    }
    if (e + q < end) {  // masked tail
        int s0 = csr_src[e + q];
        uint4 v0 = *(const uint4*)(xwh + ((s0 << 5) | oj));
        accum8(acc, v0);
    }
#pragma unroll
    for (int m = 4; m <= 16; m <<= 1) {
#pragma unroll
        for (int k = 0; k < 8; ++k) acc[k] += __shfl_xor(acc[k], m);
    }
}

// ---------------- layer-1 gather fused with bias1+relu and the W2 transform ---------------
__global__ __launch_bounds__(256) void k_gather_xw2(const int* __restrict__ rowstart,
                                                    const float* __restrict__ dinv,
                                                    const int* __restrict__ csr_src,
                                                    const __half* __restrict__ xwh1,
                                                    const float* __restrict__ b1,
                                                    const float* __restrict__ W2,
                                                    __half* __restrict__ xwh2) {
    __shared__ float sW2[HID * HID];
    __shared__ float sA[8][33];
    __shared__ float sH[8][33];
    for (int i = threadIdx.x; i < HID * HID; i += 256) sW2[i] = W2[i];

    int ln = threadIdx.x >> 5;
    int node = blockIdx.x * 8 + ln;
    int l = threadIdx.x & 31;
    int q = l >> 2;
    int oj = (l & 3) << 3;

    float acc[8];
    edge_accum8(rowstart[node], rowstart[node + 1], q, oj, csr_src, xwh1, acc);
    if (q == 0) {
#pragma unroll
        for (int k = 0; k < 8; ++k) sA[ln][oj + k] = acc[k];
    }
    __syncthreads();

    int j = l;
    float dd = dinv[node];
    float hv = dd * (sA[ln][j] + __half2float(xwh1[node * HID + j])) + b1[j];
    sH[ln][j] = hv > 0.0f ? hv : 0.0f;
    __syncthreads();

    float a2 = 0.0f;
#pragma unroll
    for (int k = 0; k < HID; ++k) a2 += sH[ln][k] * sW2[k * HID + j];
    xwh2[node * HID + j] = __float2half(dd * a2);
}

// ---------------- layer-2 gather fused with bias2+relu and the output MLP ----------------
__global__ __launch_bounds__(256) void k_gather_mlp(const int* __restrict__ rowstart,
                                                    const float* __restrict__ dinv,
                                                    const int* __restrict__ csr_src,
                                                    const __half* __restrict__ xwh,
                                                    const float* __restrict__ b2,
                                                    const float* __restrict__ Wo1,
                                                    const float* __restrict__ bo1,
                                                    const float* __restrict__ Wo2,
                                                    const float* __restrict__ bo2,
                                                    float* __restrict__ out) {
    __shared__ float sW1[HID * HID2];
    __shared__ float sb1[HID2];
    __shared__ float sW2v[HID2];
    __shared__ float sb2[HID];
    __shared__ float sA[8][33];
    __shared__ float sH[8][33];
    for (int i = threadIdx.x; i < HID * HID2; i += 256) sW1[i] = Wo1[i];
    if (threadIdx.x < HID2) {
        sb1[threadIdx.x] = bo1[threadIdx.x];
        sW2v[threadIdx.x] = Wo2[threadIdx.x];
    }
    if (threadIdx.x < HID) sb2[threadIdx.x] = b2[threadIdx.x];

    int ln = threadIdx.x >> 5;
    int node = blockIdx.x * 8 + ln;
    int l = threadIdx.x & 31;
    int q = l >> 2;
    int oj = (l & 3) << 3;

    float acc[8];
    edge_accum8(rowstart[node], rowstart[node + 1], q, oj, csr_src, xwh, acc);
    if (q == 0) {
#pragma unroll
        for (int k = 0; k < 8; ++k) sA[ln][oj + k] = acc[k];
    }
    __syncthreads();

    int j = l;
    float dd = dinv[node];
    float hv = dd * (sA[ln][j] + __half2float(xwh[node * HID + j])) + sb2[j];
    sH[ln][j] = hv > 0.0f ? hv : 0.0f;
    __syncthreads();

    float val = 0.0f;
    if (j < HID2) {
        float a = sb1[j];
#pragma unroll
        for (int k = 0; k < HID; ++k) a += sH[ln][k] * sW1[k * HID2 + j];
        a = a > 0.0f ? a : (expf(a) - 1.0f);  // elu alpha=1
        val = a * sW2v[j];
    }
#pragma unroll
    for (int d = 16; d >= 1; d >>= 1) val += __shfl_down(val, d, 32);
    if (j == 0) out[node] = val + bo2[0];
}

extern "C" void kernel_launch(void* const* d_in, const int* in_sizes, int n_in,
                              void* d_out, int out_size, void* d_ws, size_t ws_size,
                              hipStream_t stream) {
    const float* x   = (const float*)d_in[0];
    const int*   ei  = (const int*)d_in[1];
    const float* W1  = (const float*)d_in[3];
    const float* b1  = (const float*)d_in[4];
    const float* W2  = (const float*)d_in[5];
    const float* b2  = (const float*)d_in[6];
    const float* Wo1 = (const float*)d_in[7];
    const float* bo1 = (const float*)d_in[8];
    const float* Wo2 = (const float*)d_in[9];
    const float* bo2 = (const float*)d_in[10];
    float* out = (float*)d_out;

    // ws layout (4B units):
    // colsum[512] | binbase[512] | rowstart[SCHUNK] | dinv[SCHUNK]
    // | csr_src[E] (cnthist[NB*NCH]=1.2MB aliases here; dead before binfill writes)
    // | binbuf[E] | XWH1[N*HID fp16] | XWH2[N*HID fp16]
    int*      colsum   = (int*)d_ws;
    int*      binbase  = colsum + 512;
    int*      rowstart = binbase + 512;
    float*    dinv     = (float*)(rowstart + SCHUNK);
    int*      csr_src  = (int*)(dinv + SCHUNK);
    unsigned* binbuf   = (unsigned*)(csr_src + N_EDGES);
    __half*   XWH1     = (__half*)(binbuf + N_EDGES);
    __half*   XWH2     = XWH1 + (size_t)N_NODES * HID;
    int*      cnthist  = csr_src;   // alias: NB*NCH = 305762 ints << N_EDGES

    const int BT = 256;
    int gNH  = (N_NODES * HID + BT - 1) / BT;       // 12500
    int gG   = N_NODES / 8;                         // 12500 (exact)

    // binned CSR build: hist -> colscan -> binscan -> staged scatter -> fill
    k_hist      <<<NCH, BT, 0, stream>>>(ei, cnthist);
    k_colscan   <<<NB, BT, 0, stream>>>(cnthist, colsum);
    k_scanbins  <<<1, 512, 0, stream>>>(colsum, binbase);
    k_binscatter<<<NCH, 512, 0, stream>>>(ei, binbase, cnthist, binbuf);
    k_binfill   <<<2 * NB, BT, 0, stream>>>(binbuf, binbase, rowstart, dinv, csr_src);

    // layer 1 (+ fused W2): XWH1 = fp16(dinv.*(x@W1)); XWH2 = fp16(dinv.*(relu(gather+b1)@W2))
    k_xw1<<<gNH, BT, 0, stream>>>(x, W1, dinv, XWH1);
    k_gather_xw2<<<gG, BT, 0, stream>>>(rowstart, dinv, csr_src, XWH1, b1, W2, XWH2);

    // layer 2 + head: out = MLP(relu(dinv.*gather(XWH2) + b2))
    k_gather_mlp<<<gG, BT, 0, stream>>>(rowstart, dinv, csr_src, XWH2,
                                        b2, Wo1, bo1, Wo2, bo2, out);
}